// Round 4
// baseline (545.069 us; speedup 1.0000x reference)
//
#include <hip/hip_runtime.h>
#include <float.h>

#define KCODES 512
#define GDIM 64
#define TAU 2.0e-3f   // flag gap threshold on s = e2 - 2*dot (same scale as d-gaps)

// ---- workspace layout (floats) ----
// embT : [0, 32768)        512 codes x 64 dims, transposed weight
// e2   : [32768, 33280)    per-code squared norm
// cnt  : int at float-index 33280
// list : ints from 33281   flagged (grp<<16|pos), capacity 262144

__global__ void prep_kernel(const float* __restrict__ w,
                            float* __restrict__ embT,
                            float* __restrict__ e2,
                            int* __restrict__ cnt) {
    int k = blockIdx.x * blockDim.x + threadIdx.x;
    if (k == 0) *cnt = 0;
    if (k >= KCODES) return;
    float s = 0.0f;
    for (int g = 0; g < GDIM; ++g) {
        float v = w[g * KCODES + k];
        embT[k * GDIM + g] = v;
        s = __fadd_rn(s, __fmul_rn(v, v));
    }
    e2[k] = s;
}

// Pass A: 1 position/thread. The code vector for iteration k is wave-uniform,
// so embT reads scalarize to s_load_dwordx16 -> SGPRs; v_fmac takes the SGPR
// operand directly. No LDS, no e-VGPRs -> xr[64] fits in arch VGPRs without
// the round-3 AGPR spill (VGPR_Count=60 + accvgpr shuffle tax, 3x VALU).
// launch_bounds(256,5): 102-VGPR cap, 20 waves/CU to hide s_load waits.
__launch_bounds__(256, 5)
__global__ void vq_kernel(const float* __restrict__ x,
                          const float* __restrict__ embT,
                          const float* __restrict__ e2,
                          float* __restrict__ out_res,
                          float* __restrict__ out_arg,
                          int* __restrict__ cnt,
                          int* __restrict__ list) {
    const int t = threadIdx.x;
    const int blk = blockIdx.x;
    const int grp = blk >> 8;                     // 256 blocks per group
    const int pos = ((blk & 255) << 8) + t;       // 0..65535 within group
    const int b = pos >> 10;
    const int sidx = pos & 1023;

    const float* xp = x + (size_t)b * 262144 + (size_t)grp * 65536 + sidx;

    float xr[GDIM];
#pragma unroll
    for (int g = 0; g < GDIM; ++g) xr[g] = xp[g * 1024];   // coalesced dword

    float best = FLT_MAX, sec = FLT_MAX;
    int arg = 0;

    for (int k = 0; k < KCODES; ++k) {
        const float* ec = embT + k * GDIM;        // wave-uniform address
        float p0 = 0.f, p1 = 0.f, p2 = 0.f, p3 = 0.f;
#pragma unroll
        for (int g = 0; g < GDIM; g += 4) {
            p0 = __fmaf_rn(xr[g + 0], ec[g + 0], p0);   // s_load + v_fmac(s,v)
            p1 = __fmaf_rn(xr[g + 1], ec[g + 1], p1);
            p2 = __fmaf_rn(xr[g + 2], ec[g + 2], p2);
            p3 = __fmaf_rn(xr[g + 3], ec[g + 3], p3);
        }
        float dot = (p0 + p1) + (p2 + p3);
        float s = __fmaf_rn(-2.0f, dot, e2[k]);   // e2[k] also uniform -> SGPR
        if (s < best) { sec = best; best = s; arg = k; }
        else if (s < sec) { sec = s; }
    }

    // Epilogue: result = emb[:, argmin] * 0.5 (exact). Stores coalesced dword.
    float* rp = out_res + (size_t)b * 262144 + (size_t)grp * 65536 + sidx;
    const float* ev = embT + (size_t)arg * GDIM;
#pragma unroll
    for (int g = 0; g < GDIM; g += 4) {
        float4 q = *(const float4*)(ev + g);           // L2-hot, 16B
        rp[(g + 0) * 1024] = q.x * 0.5f;
        rp[(g + 1) * 1024] = q.y * 0.5f;
        rp[(g + 2) * 1024] = q.z * 0.5f;
        rp[(g + 3) * 1024] = q.w * 0.5f;
    }
    out_arg[(size_t)b * 4096 + (size_t)grp * 1024 + sidx] = (float)arg;

    if (sec - best <= TAU) { int i = atomicAdd(cnt, 1); list[i] = (grp << 16) | pos; }
}

// Pass B: exact f64 re-scan of flagged positions (verified correct, rounds
// 2-3). One wave per position; lexicographic (d,k) reduce.
__launch_bounds__(256)
__global__ void fix_kernel(const float* __restrict__ x,
                           const float* __restrict__ embT,
                           const int* __restrict__ cnt,
                           const int* __restrict__ list,
                           float* __restrict__ out_res,
                           float* __restrict__ out_arg) {
    const int lane = threadIdx.x & 63;
    const int wave = (blockIdx.x * blockDim.x + threadIdx.x) >> 6;
    const int nwaves = (gridDim.x * blockDim.x) >> 6;
    const int n = *cnt;

    for (int i = wave; i < n; i += nwaves) {
        const int gp = list[i];
        const int grp = gp >> 16;
        const int pos = gp & 0xffff;
        const int b = pos >> 10;
        const int sidx = pos & 1023;

        const float* xp = x + (size_t)b * 262144 + (size_t)grp * 65536 + sidx;
        float xr[GDIM];
#pragma unroll
        for (int g = 0; g < GDIM; ++g) xr[g] = xp[g * 1024];

        double a = 0.0;
#pragma unroll
        for (int g = 0; g < GDIM; ++g) a += (double)xr[g] * (double)xr[g];

        double bd = DBL_MAX;
        int bk = 0;
        for (int m = 0; m < KCODES / 64; ++m) {
            const int k = lane + m * 64;
            const float* er = embT + (size_t)k * GDIM;
            double dot = 0.0, ee = 0.0;
#pragma unroll
            for (int g = 0; g < GDIM; g += 4) {
                float4 e4 = *(const float4*)(er + g);
                dot += (double)xr[g + 0] * (double)e4.x;
                dot += (double)xr[g + 1] * (double)e4.y;
                dot += (double)xr[g + 2] * (double)e4.z;
                dot += (double)xr[g + 3] * (double)e4.w;
                ee  += (double)e4.x * (double)e4.x;
                ee  += (double)e4.y * (double)e4.y;
                ee  += (double)e4.z * (double)e4.z;
                ee  += (double)e4.w * (double)e4.w;
            }
            double d = (a - 2.0 * dot) + ee;
            if (d < bd) { bd = d; bk = k; }
        }
        for (int off = 32; off > 0; off >>= 1) {
            double od = __shfl_down(bd, off, 64);
            int    ok = __shfl_down(bk, off, 64);
            if (od < bd || (od == bd && ok < bk)) { bd = od; bk = ok; }
        }
        bk = __shfl(bk, 0, 64);

        if (lane == 0)
            out_arg[(size_t)b * 4096 + (size_t)grp * 1024 + sidx] = (float)bk;
        out_res[(size_t)b * 262144 + (size_t)grp * 65536 + (size_t)lane * 1024 + sidx] =
            embT[(size_t)bk * GDIM + lane] * 0.5f;
    }
}

extern "C" void kernel_launch(void* const* d_in, const int* in_sizes, int n_in,
                              void* d_out, int out_size, void* d_ws, size_t ws_size,
                              hipStream_t stream) {
    const float* x = (const float*)d_in[0];      // (64,256,32,32) f32
    const float* w = (const float*)d_in[1];      // (64,512) f32
    float* out_res = (float*)d_out;              // 16777216 floats
    float* out_arg = (float*)d_out + 16777216;   // 262144 floats
    float* embT = (float*)d_ws;
    float* e2   = embT + KCODES * GDIM;
    int*   cnt  = (int*)(e2 + KCODES);
    int*   list = cnt + 1;

    prep_kernel<<<2, 256, 0, stream>>>(w, embT, e2, cnt);
    vq_kernel<<<1024, 256, 0, stream>>>(x, embT, e2, out_res, out_arg, cnt, list);
    fix_kernel<<<256, 256, 0, stream>>>(x, embT, cnt, list, out_res, out_arg);
}

// Round 5
// 495.248 us; speedup vs baseline: 1.1006x; 1.1006x over previous
//
#include <hip/hip_runtime.h>
#include <float.h>

#define KCODES 512
#define GDIM 64
#define CHUNK 128
#define TAU 2.0e-3f   // flag gap threshold on s = e2 - 2*dot (validated r3/r4: absmax 0)

// ---- workspace layout (floats) ----
// embT : [0, 32768)        512 codes x 64 dims, transposed weight
// e2   : [32768, 33280)    per-code squared norm
// cnt  : int at float-index 33280
// list : ints from 33281   flagged (grp<<16|pos), capacity 262144

__global__ void prep_kernel(const float* __restrict__ w,
                            float* __restrict__ embT,
                            float* __restrict__ e2,
                            int* __restrict__ cnt) {
    int k = blockIdx.x * blockDim.x + threadIdx.x;
    if (k == 0) *cnt = 0;
    if (k >= KCODES) return;
    float s = 0.0f;
    for (int g = 0; g < GDIM; ++g) {
        float v = w[g * KCODES + k];
        embT[k * GDIM + g] = v;
        s = __fadd_rn(s, __fmul_rn(v, v));
    }
    e2[k] = s;
}

// Pass A: 1 position/thread, codebook chunked through LDS, e read as wave-
// uniform broadcast ds_read_b128 (LDS broadcast = same-addr, conflict-free,
// ~128B/cyc/CU pipe -- the only pipe with headroom; r4 showed the scalar-K$
// path saturates at 37% VALUBusy).
// launch_bounds(256,3): ~170-reg cap so xr[64] + a full in-flight e-batch
// (16 float4) fit in ARCH VGPRs. r3's (256,4)=128 cap AGPR-spilled xr
// (VGPR_Count=60, 3x VALU move tax); r4's (256,5)=102 cap did too (VGPR=40).
// 3 waves/SIMD + fine-grained lgkmcnt hide broadcast latency under the
// 128-cyc/k FMA stream.
__launch_bounds__(256, 3)
__global__ void vq_kernel(const float* __restrict__ x,
                          const float* __restrict__ embT,
                          const float* __restrict__ e2,
                          float* __restrict__ out_res,
                          float* __restrict__ out_arg,
                          int* __restrict__ cnt,
                          int* __restrict__ list) {
    __shared__ float s_emb[CHUNK * GDIM];
    __shared__ float s_e2[CHUNK];

    const int t = threadIdx.x;
    const int blk = blockIdx.x;
    const int grp = blk >> 8;                     // 256 blocks per group
    const int pos = ((blk & 255) << 8) + t;       // 0..65535 within group
    const int b = pos >> 10;
    const int sidx = pos & 1023;

    const float* xp = x + (size_t)b * 262144 + (size_t)grp * 65536 + sidx;

    float xr[GDIM];
#pragma unroll
    for (int g = 0; g < GDIM; ++g) xr[g] = xp[g * 1024];   // coalesced dword

    float best = FLT_MAX, sec = FLT_MAX;
    int arg = 0;

    for (int c = 0; c < KCODES / CHUNK; ++c) {
        __syncthreads();
        const float4* src = (const float4*)(embT + (size_t)c * CHUNK * GDIM);
        float4* dst = (float4*)s_emb;
#pragma unroll
        for (int i = 0; i < (CHUNK * GDIM / 4) / 256; ++i)
            dst[t + i * 256] = src[t + i * 256];
        if (t < CHUNK) s_e2[t] = e2[c * CHUNK + t];
        __syncthreads();

        for (int k = 0; k < CHUNK; ++k) {
            const float* ec = s_emb + k * GDIM;
            float p0 = 0.f, p1 = 0.f, p2 = 0.f, p3 = 0.f;
#pragma unroll
            for (int g = 0; g < GDIM; g += 4) {
                float4 e = *(const float4*)(ec + g);   // broadcast ds_read_b128
                p0 = __fmaf_rn(xr[g + 0], e.x, p0);
                p1 = __fmaf_rn(xr[g + 1], e.y, p1);
                p2 = __fmaf_rn(xr[g + 2], e.z, p2);
                p3 = __fmaf_rn(xr[g + 3], e.w, p3);
            }
            float dot = (p0 + p1) + (p2 + p3);
            float s = __fmaf_rn(-2.0f, dot, s_e2[k]);
            int kk = c * CHUNK + k;
            if (s < best) { sec = best; best = s; arg = kk; }
            else if (s < sec) { sec = s; }
        }
    }

    // Epilogue: result = emb[:, argmin] * 0.5 (exact). Stores coalesced dword.
    float* rp = out_res + (size_t)b * 262144 + (size_t)grp * 65536 + sidx;
    const float* ev = embT + (size_t)arg * GDIM;
#pragma unroll
    for (int g = 0; g < GDIM; g += 4) {
        float4 q = *(const float4*)(ev + g);           // L2-hot, 16B
        rp[(g + 0) * 1024] = q.x * 0.5f;
        rp[(g + 1) * 1024] = q.y * 0.5f;
        rp[(g + 2) * 1024] = q.z * 0.5f;
        rp[(g + 3) * 1024] = q.w * 0.5f;
    }
    out_arg[(size_t)b * 4096 + (size_t)grp * 1024 + sidx] = (float)arg;

    if (sec - best <= TAU) { int i = atomicAdd(cnt, 1); list[i] = (grp << 16) | pos; }
}

// Pass B: exact f64 re-scan of flagged positions (verified correct, rounds
// 2-4). One wave per position; lexicographic (d,k) reduce.
__launch_bounds__(256)
__global__ void fix_kernel(const float* __restrict__ x,
                           const float* __restrict__ embT,
                           const int* __restrict__ cnt,
                           const int* __restrict__ list,
                           float* __restrict__ out_res,
                           float* __restrict__ out_arg) {
    const int lane = threadIdx.x & 63;
    const int wave = (blockIdx.x * blockDim.x + threadIdx.x) >> 6;
    const int nwaves = (gridDim.x * blockDim.x) >> 6;
    const int n = *cnt;

    for (int i = wave; i < n; i += nwaves) {
        const int gp = list[i];
        const int grp = gp >> 16;
        const int pos = gp & 0xffff;
        const int b = pos >> 10;
        const int sidx = pos & 1023;

        const float* xp = x + (size_t)b * 262144 + (size_t)grp * 65536 + sidx;
        float xr[GDIM];
#pragma unroll
        for (int g = 0; g < GDIM; ++g) xr[g] = xp[g * 1024];

        double a = 0.0;
#pragma unroll
        for (int g = 0; g < GDIM; ++g) a += (double)xr[g] * (double)xr[g];

        double bd = DBL_MAX;
        int bk = 0;
        for (int m = 0; m < KCODES / 64; ++m) {
            const int k = lane + m * 64;
            const float* er = embT + (size_t)k * GDIM;
            double dot = 0.0, ee = 0.0;
#pragma unroll
            for (int g = 0; g < GDIM; g += 4) {
                float4 e4 = *(const float4*)(er + g);
                dot += (double)xr[g + 0] * (double)e4.x;
                dot += (double)xr[g + 1] * (double)e4.y;
                dot += (double)xr[g + 2] * (double)e4.z;
                dot += (double)xr[g + 3] * (double)e4.w;
                ee  += (double)e4.x * (double)e4.x;
                ee  += (double)e4.y * (double)e4.y;
                ee  += (double)e4.z * (double)e4.z;
                ee  += (double)e4.w * (double)e4.w;
            }
            double d = (a - 2.0 * dot) + ee;
            if (d < bd) { bd = d; bk = k; }
        }
        for (int off = 32; off > 0; off >>= 1) {
            double od = __shfl_down(bd, off, 64);
            int    ok = __shfl_down(bk, off, 64);
            if (od < bd || (od == bd && ok < bk)) { bd = od; bk = ok; }
        }
        bk = __shfl(bk, 0, 64);

        if (lane == 0)
            out_arg[(size_t)b * 4096 + (size_t)grp * 1024 + sidx] = (float)bk;
        out_res[(size_t)b * 262144 + (size_t)grp * 65536 + (size_t)lane * 1024 + sidx] =
            embT[(size_t)bk * GDIM + lane] * 0.5f;
    }
}

extern "C" void kernel_launch(void* const* d_in, const int* in_sizes, int n_in,
                              void* d_out, int out_size, void* d_ws, size_t ws_size,
                              hipStream_t stream) {
    const float* x = (const float*)d_in[0];      // (64,256,32,32) f32
    const float* w = (const float*)d_in[1];      // (64,512) f32
    float* out_res = (float*)d_out;              // 16777216 floats
    float* out_arg = (float*)d_out + 16777216;   // 262144 floats
    float* embT = (float*)d_ws;
    float* e2   = embT + KCODES * GDIM;
    int*   cnt  = (int*)(e2 + KCODES);
    int*   list = cnt + 1;

    prep_kernel<<<2, 256, 0, stream>>>(w, embT, e2, cnt);
    vq_kernel<<<1024, 256, 0, stream>>>(x, embT, e2, out_res, out_arg, cnt, list);
    fix_kernel<<<256, 256, 0, stream>>>(x, embT, cnt, list, out_res, out_arg);
}

// Round 7
// 301.314 us; speedup vs baseline: 1.8090x; 1.6436x over previous
//
#include <hip/hip_runtime.h>
#include <float.h>

#define KCODES 512
#define GDIM 64
#define TAU 2.0e-3f   // validated r2-r5 (absmax 0); pass-A err budget here ~3e-4

typedef __attribute__((ext_vector_type(8))) short short8;   // 8 bf16 = 4 VGPR
typedef __attribute__((ext_vector_type(4))) float floatx4;  // MFMA C/D

// ---- workspace layout ----
// embT   f32[512*64]     float idx [0, 32768)
// e2     f32[512]        [32768, 33280)
// e2d    f64[512]        [33280, 34304)  (byte 133120, 8-aligned)
// emb_hi bf16[512*64]    [34304, 50688)  (code-major, 64/row)
// emb_lo bf16[512*64]    [50688, 67072)
// bitmap u32[8192]       [67072, 75264)  (one bit per (grp,pos))

__device__ __forceinline__ void bf16split(float x, short& hi, short& lo) {
    unsigned u = __float_as_uint(x);
    unsigned h = (u + 0x7fffu + ((u >> 16) & 1u)) >> 16;   // RNE to bf16
    hi = (short)h;
    float hf = __uint_as_float(h << 16);
    float l = x - hf;                                      // exact in f32
    unsigned ul = __float_as_uint(l);
    lo = (short)((ul + 0x7fffu + ((ul >> 16) & 1u)) >> 16);
}

// grid 32x256 = 8192 threads: zero bitmap; first 512 threads prep one code each.
__global__ void prep_kernel(const float* __restrict__ w,
                            float* __restrict__ embT,
                            float* __restrict__ e2,
                            double* __restrict__ e2d,
                            short* __restrict__ emb_hi,
                            short* __restrict__ emb_lo,
                            unsigned* __restrict__ bitmap) {
    int tid = blockIdx.x * 256 + threadIdx.x;
    bitmap[tid] = 0u;                       // exactly 8192 words
    if (tid >= KCODES) return;
    float s = 0.0f; double sd = 0.0;
    for (int g = 0; g < GDIM; ++g) {
        float v = w[g * KCODES + tid];
        embT[tid * GDIM + g] = v;
        short h, l; bf16split(v, h, l);
        emb_hi[tid * GDIM + g] = h;
        emb_lo[tid * GDIM + g] = l;
        s = __fadd_rn(s, __fmul_rn(v, v));
        sd += (double)v * (double)v;
    }
    e2[tid] = s;
    e2d[tid] = sd;
}

// Pass A (MFMA): wave = 32 positions (2 m-tiles), all 512 codes in 4 LDS
// chunks of 128. dot = hi.hi + hi.lo + lo.hi split-bf16 (err <= ~3e-4 << TAU).
// A-frag: A[m=lane&15][k=quad*8+j] (doc-verified); B symmetric
// B[k=quad*8+j][n=lane&15] (A/B share the k-map -> any common HW k-perm
// cancels in the dot). C/D: m=quad*4+reg, n=lane&15 (doc-verified).
// LDS rows padded 64->72 shorts (16B-aligned rows; per 16-lane phase each
// start-bank is hit exactly 2x -> at the 1024B/8clk b128 floor).
__launch_bounds__(256, 1)
__global__ void vq_kernel(const float* __restrict__ x,
                          const float* __restrict__ embT,
                          const float* __restrict__ e2,
                          const short* __restrict__ emb_hi,
                          const short* __restrict__ emb_lo,
                          float* __restrict__ out_res,
                          float* __restrict__ out_arg,
                          unsigned* __restrict__ bitmap) {
    __shared__ short s_hi[128 * 72];
    __shared__ short s_lo[128 * 72];
    __shared__ float s_e2c[128];
    __shared__ int   s_arg[4 * 32];

    const int t = threadIdx.x;
    const int wid = t >> 6;
    const int lane = t & 63;
    const int q = lane >> 4;          // quad
    const int c = lane & 15;          // col within tile
    const int blk = blockIdx.x;
    const int grp = blk >> 9;                          // 512 blocks per group
    const int posbase = ((blk & 511) << 7) + wid * 32; // wave's 32 positions
    const int b = posbase >> 10;
    const int hwb = posbase & 1023;

    const float* xbase = x + (size_t)b * 262144 + (size_t)grp * 65536 + hwb;

    // A fragments: [mt][kt], hi and lo. 8 strided dwords each, split to bf16.
    short8 ahi[2][2], alo[2][2];
#pragma unroll
    for (int mt = 0; mt < 2; ++mt)
#pragma unroll
        for (int kt = 0; kt < 2; ++kt) {
#pragma unroll
            for (int j = 0; j < 8; ++j) {
                float xv = xbase[(kt * 32 + q * 8 + j) * 1024 + mt * 16 + c];
                short h, l; bf16split(xv, h, l);
                ahi[mt][kt][j] = h; alo[mt][kt][j] = l;
            }
        }

    float best[2][4], sec[2][4]; int arg[2][4];
#pragma unroll
    for (int mt = 0; mt < 2; ++mt)
#pragma unroll
        for (int r = 0; r < 4; ++r) { best[mt][r] = FLT_MAX; sec[mt][r] = FLT_MAX; arg[mt][r] = 0; }

    for (int ch = 0; ch < 4; ++ch) {
        const int C0 = ch * 128;
        __syncthreads();
        // Stage the full chunk: 128 rows x 8 uint4-units = 1024 units per
        // array; 256 threads x 4 iterations.  (r6 bug: i<2 staged only half
        // the chunk -> rows 64..127 garbage -> absmax 510.)
#pragma unroll
        for (int i = 0; i < 4; ++i) {
            int idx = i * 256 + t;
            int rr = idx >> 3, uu = idx & 7;
            *(uint4*)&s_hi[rr * 72 + uu * 8] =
                *(const uint4*)(emb_hi + (size_t)(C0 + rr) * 64 + uu * 8);
            *(uint4*)&s_lo[rr * 72 + uu * 8] =
                *(const uint4*)(emb_lo + (size_t)(C0 + rr) * 64 + uu * 8);
        }
        if (t < 128) s_e2c[t] = e2[C0 + t];
        __syncthreads();

        floatx4 acc[2][8];
#pragma unroll
        for (int mt = 0; mt < 2; ++mt)
#pragma unroll
            for (int nt = 0; nt < 8; ++nt) acc[mt][nt] = (floatx4){0.f, 0.f, 0.f, 0.f};

#pragma unroll
        for (int nt = 0; nt < 8; ++nt) {
            const int off = (nt * 16 + c) * 72 + q * 8;
            short8 bh0 = *(const short8*)&s_hi[off];
            short8 bh1 = *(const short8*)&s_hi[off + 32];
            short8 bl0 = *(const short8*)&s_lo[off];
            short8 bl1 = *(const short8*)&s_lo[off + 32];
#pragma unroll
            for (int mt = 0; mt < 2; ++mt) {
                floatx4 a4 = acc[mt][nt];
                a4 = __builtin_amdgcn_mfma_f32_16x16x32_bf16(alo[mt][0], bh0, a4, 0, 0, 0);
                a4 = __builtin_amdgcn_mfma_f32_16x16x32_bf16(ahi[mt][0], bl0, a4, 0, 0, 0);
                a4 = __builtin_amdgcn_mfma_f32_16x16x32_bf16(ahi[mt][0], bh0, a4, 0, 0, 0);
                a4 = __builtin_amdgcn_mfma_f32_16x16x32_bf16(alo[mt][1], bh1, a4, 0, 0, 0);
                a4 = __builtin_amdgcn_mfma_f32_16x16x32_bf16(ahi[mt][1], bl1, a4, 0, 0, 0);
                a4 = __builtin_amdgcn_mfma_f32_16x16x32_bf16(ahi[mt][1], bh1, a4, 0, 0, 0);
                acc[mt][nt] = a4;
            }
        }

        // chunk epilogue: s = e2 - 2*dot, running (best, sec, arg) per m-slot
#pragma unroll
        for (int mt = 0; mt < 2; ++mt)
#pragma unroll
            for (int nt = 0; nt < 8; ++nt) {
                float se2 = s_e2c[nt * 16 + c];
                int n = C0 + nt * 16 + c;
#pragma unroll
                for (int r = 0; r < 4; ++r) {
                    float s = __fmaf_rn(-2.0f, acc[mt][nt][r], se2);
                    if (s < best[mt][r]) { sec[mt][r] = best[mt][r]; best[mt][r] = s; arg[mt][r] = n; }
                    else if (s < sec[mt][r]) sec[mt][r] = s;
                }
            }
    }

    // cross-lane merge over the 16 cols (ties -> gap 0 -> flagged -> f64 fix)
#pragma unroll
    for (int mt = 0; mt < 2; ++mt)
#pragma unroll
        for (int r = 0; r < 4; ++r) {
            float b_ = best[mt][r], s_ = sec[mt][r]; int a_ = arg[mt][r];
#pragma unroll
            for (int sh = 1; sh < 16; sh <<= 1) {
                float ob = __shfl_xor(b_, sh, 64);
                float os = __shfl_xor(s_, sh, 64);
                int   oa = __shfl_xor(a_, sh, 64);
                if (ob < b_) { s_ = fminf(b_, os); b_ = ob; a_ = oa; }
                else         { s_ = fminf(s_, ob); }
            }
            if (c == 0) {
                int p = mt * 16 + q * 4 + r;          // 0..31 within wave
                s_arg[wid * 32 + p] = a_;
                if (s_ - b_ <= TAU) {
                    int gidx = grp * 65536 + posbase + p;
                    atomicOr(&bitmap[gidx >> 5], 1u << (gidx & 31));
                }
            }
        }
    __syncthreads();

    // argmin output: block's 128 positions, one coalesced pass
    if (t < 128) {
        int bp = ((blk & 511) << 7) + t;
        out_arg[(size_t)(bp >> 10) * 4096 + (size_t)grp * 1024 + (bp & 1023)] =
            (float)s_arg[t];
    }

    // result output: wave's 32 positions, lane = (gi, p), stores 2x128B runs
    {
        int p = lane & 31, gi = lane >> 5;
        int ac = s_arg[wid * 32 + p];
        const float* ev = embT + (size_t)ac * GDIM;
        float* rp = out_res + (size_t)b * 262144 + (size_t)grp * 65536 + hwb + p;
#pragma unroll
        for (int it = 0; it < 32; ++it) {
            int g = it * 2 + gi;
            rp[(size_t)g * 1024] = ev[g] * 0.5f;
        }
    }
}

// Pass B: exact f64 re-rank of flagged positions (bitmap). Rank by
// s = e2d[k] - 2*dot (the per-position |x|^2 shift is rank-irrelevant).
__launch_bounds__(256)
__global__ void fix_kernel(const float* __restrict__ x,
                           const float* __restrict__ embT,
                           const double* __restrict__ e2d,
                           const unsigned* __restrict__ bitmap,
                           float* __restrict__ out_res,
                           float* __restrict__ out_arg) {
    const int lane = threadIdx.x & 63;
    const int wave = (blockIdx.x * blockDim.x + threadIdx.x) >> 6;
    const int nwaves = (gridDim.x * blockDim.x) >> 6;

    for (int gidx = wave; gidx < 262144; gidx += nwaves) {
        if (!((bitmap[gidx >> 5] >> (gidx & 31)) & 1u)) continue;
        const int grp = gidx >> 16;
        const int pos = gidx & 65535;
        const int b = pos >> 10;
        const int sidx = pos & 1023;

        const float* xp = x + (size_t)b * 262144 + (size_t)grp * 65536 + sidx;
        float xr[GDIM];
#pragma unroll
        for (int g = 0; g < GDIM; ++g) xr[g] = xp[g * 1024];

        double bd = DBL_MAX;
        int bk = 0;
        for (int m = 0; m < KCODES / 64; ++m) {
            const int k = lane + m * 64;
            const float* er = embT + (size_t)k * GDIM;
            double dot = 0.0;
#pragma unroll
            for (int g = 0; g < GDIM; g += 4) {
                float4 e4 = *(const float4*)(er + g);
                dot += (double)xr[g + 0] * (double)e4.x;
                dot += (double)xr[g + 1] * (double)e4.y;
                dot += (double)xr[g + 2] * (double)e4.z;
                dot += (double)xr[g + 3] * (double)e4.w;
            }
            double s = e2d[k] - 2.0 * dot;
            if (s < bd) { bd = s; bk = k; }            // ascending k per lane
        }
        for (int off = 32; off > 0; off >>= 1) {       // lexicographic (s, k)
            double od = __shfl_down(bd, off, 64);
            int    ok = __shfl_down(bk, off, 64);
            if (od < bd || (od == bd && ok < bk)) { bd = od; bk = ok; }
        }
        bk = __shfl(bk, 0, 64);

        if (lane == 0)
            out_arg[(size_t)b * 4096 + (size_t)grp * 1024 + sidx] = (float)bk;
        out_res[(size_t)b * 262144 + (size_t)grp * 65536 + (size_t)lane * 1024 + sidx] =
            embT[(size_t)bk * GDIM + lane] * 0.5f;
    }
}

extern "C" void kernel_launch(void* const* d_in, const int* in_sizes, int n_in,
                              void* d_out, int out_size, void* d_ws, size_t ws_size,
                              hipStream_t stream) {
    const float* x = (const float*)d_in[0];      // (64,256,32,32) f32
    const float* w = (const float*)d_in[1];      // (64,512) f32
    float* out_res = (float*)d_out;              // 16777216 floats
    float* out_arg = (float*)d_out + 16777216;   // 262144 floats

    float*    embT   = (float*)d_ws;
    float*    e2     = embT + 32768;
    double*   e2d    = (double*)((char*)d_ws + (size_t)33280 * 4);
    short*    emb_hi = (short*)((float*)d_ws + 34304);
    short*    emb_lo = (short*)((float*)d_ws + 50688);
    unsigned* bitmap = (unsigned*)((float*)d_ws + 67072);

    prep_kernel<<<32, 256, 0, stream>>>(w, embT, e2, e2d, emb_hi, emb_lo, bitmap);
    vq_kernel<<<2048, 256, 0, stream>>>(x, embT, e2, emb_hi, emb_lo,
                                        out_res, out_arg, bitmap);
    fix_kernel<<<1024, 256, 0, stream>>>(x, embT, e2d, bitmap, out_res, out_arg);
}